// Round 3
// baseline (100.064 us; speedup 1.0000x reference)
//
#include <hip/hip_runtime.h>
#include <hip/hip_bf16.h>
#include <hip/hip_cooperative_groups.h>

#define DIM 256
#define NAGENT 64
#define NBATCH 256

typedef __bf16 bf16_t;
typedef bf16_t bf16x8 __attribute__((ext_vector_type(8)));
typedef float f32x4 __attribute__((ext_vector_type(4)));

// One cooperative kernel. Block b:
//  waves 0-3: stream h[b] once (col-per-thread), build g (bf16, swizzled LDS)
//             g[j,k] = (sum_i h[b,i,k] - h[b,j,k]) / 63
//  waves 4-7: prep row b: t1 = Wh[b]@Ws ; Wc[b] = t1@Wa ; bc[b]
//  grid.sync(); then 8-wave MFMA GEMM: out[b] = relu(g @ Wc^T + bc)
__global__ __launch_bounds__(512) void mac_coop_kernel(
    const float* __restrict__ h,
    const float* __restrict__ Wh, const float* __restrict__ Ws,
    const float* __restrict__ Wa, const float* __restrict__ ba,
    const float* __restrict__ bs, const float* __restrict__ bh,
    bf16_t* __restrict__ Wc, float* __restrict__ bcw,
    float* __restrict__ out) {
  const int b = blockIdx.x;
  const int t = threadIdx.x;

  __shared__ __align__(16) bf16_t g[NAGENT * DIM];  // 32 KB, XOR-swizzled
  __shared__ float t1l[DIM];                        // 1 KB

  const float* hb = h + (size_t)b * NAGENT * DIM;

  if (t < 256) {
    // ---- waves 0-3: h pass. Thread owns column c for all 64 rows. ----
    const int c = t;
    float hs = 0.f;
    // pass 1: stream h, accumulate column sum, stash bf16(h) in g (swizzled)
#pragma unroll 8
    for (int r = 0; r < 64; ++r) {
      const float v = hb[r * DIM + c];
      hs += v;
      g[r * DIM + (c ^ ((r & 7) << 3))] = (bf16_t)v;
    }
    // pass 2: rewrite own column: g = (hs - h) / 63
    const float inv = 1.0f / 63.0f;
#pragma unroll 8
    for (int r = 0; r < 64; ++r) {
      const int idx = r * DIM + (c ^ ((r & 7) << 3));
      const float v = (float)g[idx];
      g[idx] = (bf16_t)((hs - v) * inv);
    }
  } else {
    // ---- waves 4-7 stage 1: t1[j] = sum_k Wh[b][k] * Ws[k][j] ----
    const int j = t - 256;
    const float* whr = Wh + b * DIM;
    float acc = 0.f;
#pragma unroll 8
    for (int k = 0; k < DIM; ++k) acc += whr[k] * Ws[k * DIM + j];
    t1l[j] = acc;
  }
  __syncthreads();

  if (t >= 256) {
    // ---- stage 2: Wc[b][j] = sum_k t1[k] * Wa[k][j] ----
    const int j = t - 256;
    float acc = 0.f;
#pragma unroll 8
    for (int k = 0; k < DIM; ++k) acc += t1l[k] * Wa[k * DIM + j];
    Wc[b * DIM + j] = (bf16_t)acc;
    // bc[b] = dot(t1,ba) + dot(Wh[b],bs) + bh[b] — wave 4 only, shuffle-reduce
    if (j < 64) {
      const float* whr = Wh + b * DIM;
      float p = 0.f;
#pragma unroll
      for (int q = 0; q < 4; ++q) {
        const int jj = j + q * 64;
        p += t1l[jj] * ba[jj] + whr[jj] * bs[jj];
      }
#pragma unroll
      for (int s = 32; s > 0; s >>= 1) p += __shfl_down(p, s, 64);
      if (j == 0) bcw[b] = p + bh[b];
    }
  }

  __threadfence();
  cooperative_groups::this_grid().sync();

  // ---- GEMM: wave w owns rows 0..63 x cols w*32..w*32+31 ----
  const int w = t >> 6, lane = t & 63;
  const int lrow = lane & 15, lgrp = lane >> 4;

  f32x4 acc[4][2];
#pragma unroll
  for (int rt = 0; rt < 4; ++rt)
#pragma unroll
    for (int ct = 0; ct < 2; ++ct) acc[rt][ct] = (f32x4){0.f, 0.f, 0.f, 0.f};

#pragma unroll
  for (int kk = 0; kk < 8; ++kk) {
    const int k0 = kk * 32 + lgrp * 8;
    bf16x8 bfrag[2];
#pragma unroll
    for (int ct = 0; ct < 2; ++ct) {
      const int col = w * 32 + ct * 16 + lrow;
      bfrag[ct] = *(const bf16x8*)&Wc[col * DIM + k0];
    }
#pragma unroll
    for (int rt = 0; rt < 4; ++rt) {
      const int arow = rt * 16 + lrow;
      const bf16x8 afrag =
          *(const bf16x8*)&g[arow * DIM + (k0 ^ ((arow & 7) << 3))];
      acc[rt][0] = __builtin_amdgcn_mfma_f32_16x16x32_bf16(afrag, bfrag[0], acc[rt][0], 0, 0, 0);
      acc[rt][1] = __builtin_amdgcn_mfma_f32_16x16x32_bf16(afrag, bfrag[1], acc[rt][1], 0, 0, 0);
    }
  }

  // ---- epilogue: C/D layout col=lane&15, row=(lane>>4)*4+reg ----
  float* ob = out + (size_t)b * NAGENT * DIM;
#pragma unroll
  for (int ct = 0; ct < 2; ++ct) {
    const int col = w * 32 + ct * 16 + lrow;
    const float bcv = bcw[col];
#pragma unroll
    for (int rt = 0; rt < 4; ++rt) {
#pragma unroll
      for (int r = 0; r < 4; ++r) {
        const int row = rt * 16 + lgrp * 4 + r;
        const float val = acc[rt][ct][r] + bcv;
        ob[row * DIM + col] = val > 0.f ? val : 0.f;
      }
    }
  }
}

extern "C" void kernel_launch(void* const* d_in, const int* in_sizes, int n_in,
                              void* d_out, int out_size, void* d_ws, size_t ws_size,
                              hipStream_t stream) {
  const float* h  = (const float*)d_in[0];  // hidden_state (16384,256)
  const float* Wa = (const float*)d_in[1];  // W_act (256,256)
  const float* ba = (const float*)d_in[2];  // b_act (256,)
  const float* Ws = (const float*)d_in[3];  // W_sum (256,256)
  const float* bs = (const float*)d_in[4];  // b_sum (256,)
  const float* Wh = (const float*)d_in[5];  // W_head (256,256)
  const float* bh = (const float*)d_in[6];  // b_head (256,)
  float* out = (float*)d_out;

  char* ws = (char*)d_ws;
  bf16_t* Wc  = (bf16_t*)ws;                 // 128 KB
  float*  bcw = (float*)(ws + 128 * 1024);   // 1 KB

  void* args[] = {(void*)&h,  (void*)&Wh, (void*)&Ws, (void*)&Wa,
                  (void*)&ba, (void*)&bs, (void*)&bh, (void*)&Wc,
                  (void*)&bcw, (void*)&out};
  hipLaunchCooperativeKernel((const void*)mac_coop_kernel, dim3(NBATCH),
                             dim3(512), args, 0, stream);
}

// Round 4
// 23.654 us; speedup vs baseline: 4.2302x; 4.2302x over previous
//
#include <hip/hip_runtime.h>
#include <hip/hip_bf16.h>

#define DIM 256
#define NAGENT 64
#define NBATCH 256

typedef __bf16 bf16_t;
typedef bf16_t bf16x4 __attribute__((ext_vector_type(4)));
typedef bf16_t bf16x8 __attribute__((ext_vector_type(8)));
typedef float f32x4 __attribute__((ext_vector_type(4)));

// Prep: block b computes row b of Wc = bf16(Wh @ Ws @ Wa) and bc[b].
// 1024 threads: jg = t&63 (4 output cols), kc = t>>6 (k-chunk of 16).
// All k-loop loads are independent float4 -> single latency exposure/stage.
__global__ __launch_bounds__(1024) void prep_kernel(
    const float* __restrict__ Wh, const float* __restrict__ Ws,
    const float* __restrict__ Wa, const float* __restrict__ ba,
    const float* __restrict__ bs, const float* __restrict__ bh,
    bf16_t* __restrict__ Wc, float* __restrict__ bcw) {
  const int b = blockIdx.x;
  const int t = threadIdx.x;
  const int jg = t & 63;
  const int kc = t >> 6;

  __shared__ float whl[DIM];        // Wh row b
  __shared__ float t1l[DIM];        // Whs row b
  __shared__ f32x4 part[16][64];    // 16 KB partials
  __shared__ float red[256];

  if (t < DIM) whl[t] = Wh[b * DIM + t];
  __syncthreads();

  // stage 1: t1 = whl @ Ws
  {
    f32x4 a = {0.f, 0.f, 0.f, 0.f};
#pragma unroll
    for (int ki = 0; ki < 16; ++ki) {
      const int k = kc * 16 + ki;
      const f32x4 w4 = *(const f32x4*)&Ws[k * DIM + jg * 4];
      a += whl[k] * w4;
    }
    part[kc][jg] = a;
  }
  __syncthreads();
  if (t < 64) {
    f32x4 s = part[0][t];
#pragma unroll
    for (int kc2 = 1; kc2 < 16; ++kc2) s += part[kc2][t];
    *(f32x4*)&t1l[t * 4] = s;
  }
  __syncthreads();

  // stage 2: Wc row = t1 @ Wa ; also bias partials
  {
    f32x4 a = {0.f, 0.f, 0.f, 0.f};
#pragma unroll
    for (int ki = 0; ki < 16; ++ki) {
      const int k = kc * 16 + ki;
      const f32x4 w4 = *(const f32x4*)&Wa[k * DIM + jg * 4];
      a += t1l[k] * w4;
    }
    if (t < 256) red[t] = t1l[t] * ba[t] + whl[t] * bs[t];
    part[kc][jg] = a;
  }
  __syncthreads();
  if (t < 64) {
    f32x4 s = part[0][t];
#pragma unroll
    for (int kc2 = 1; kc2 < 16; ++kc2) s += part[kc2][t];
    bf16x4 wb;
    wb[0] = (bf16_t)s[0]; wb[1] = (bf16_t)s[1];
    wb[2] = (bf16_t)s[2]; wb[3] = (bf16_t)s[3];
    *(bf16x4*)&Wc[b * DIM + t * 4] = wb;
    // bias reduce: wave 0 only
    float p = red[t] + red[t + 64] + red[t + 128] + red[t + 192];
#pragma unroll
    for (int s2 = 32; s2 > 0; s2 >>= 1) p += __shfl_down(p, s2, 64);
    if (t == 0) bcw[b] = p + bh[b];
  }
}

// Fused main: out[b*64+j, d] = relu( sum_k g[j,k] * Wc[d,k] + bc[d] )
// g[j,k] = (sum_i h[b,i,k] - h[b,j,k]) / 63. h read once as float4.
// GEMM mapping: wave w owns all 64 rows x cols w*32..+31 (Wc read once/block).
__global__ __launch_bounds__(512) void fused_kernel(
    const float* __restrict__ h, const bf16_t* __restrict__ Wc,
    const float* __restrict__ bcw, float* __restrict__ out) {
  const int b = blockIdx.x;
  const int t = threadIdx.x;

  __shared__ __align__(16) bf16_t g[NAGENT * DIM];  // 32 KB, XOR-swizzled
  __shared__ f32x4 ps[8][64];                       // 8 KB

  const float* hb = h + (size_t)b * NAGENT * DIM;
  const int cg = t & 63;   // cols cg*4 .. +3
  const int rg = t >> 6;   // rows rg*8 .. +7

  f32x4 v[8];
  f32x4 s4 = {0.f, 0.f, 0.f, 0.f};
#pragma unroll
  for (int i = 0; i < 8; ++i) {
    v[i] = *(const f32x4*)&hb[(rg * 8 + i) * DIM + cg * 4];
    s4 += v[i];
  }
  ps[rg][cg] = s4;
  __syncthreads();
  f32x4 hs = ps[0][cg];
#pragma unroll
  for (int r = 1; r < 8; ++r) hs += ps[r][cg];

  const float inv = 1.0f / 63.0f;
#pragma unroll
  for (int i = 0; i < 8; ++i) {
    const int row = rg * 8 + i;
    const f32x4 gv = (hs - v[i]) * inv;
    bf16x4 gb;
    gb[0] = (bf16_t)gv[0]; gb[1] = (bf16_t)gv[1];
    gb[2] = (bf16_t)gv[2]; gb[3] = (bf16_t)gv[3];
    *(bf16x4*)&g[row * DIM + ((cg * 4) ^ ((row & 7) << 3))] = gb;
  }
  __syncthreads();

  // GEMM: wave w -> cols w*32..+31, rows 0..63
  const int w = t >> 6, lane = t & 63;
  const int lrow = lane & 15, lgrp = lane >> 4;

  f32x4 acc[4][2];
#pragma unroll
  for (int rt = 0; rt < 4; ++rt)
#pragma unroll
    for (int ct = 0; ct < 2; ++ct) acc[rt][ct] = (f32x4){0.f, 0.f, 0.f, 0.f};

#pragma unroll
  for (int kk = 0; kk < 8; ++kk) {
    const int k0 = kk * 32 + lgrp * 8;
    bf16x8 bfrag[2];
#pragma unroll
    for (int ct = 0; ct < 2; ++ct) {
      const int col = w * 32 + ct * 16 + lrow;
      bfrag[ct] = *(const bf16x8*)&Wc[col * DIM + k0];
    }
#pragma unroll
    for (int rt = 0; rt < 4; ++rt) {
      const int arow = rt * 16 + lrow;
      const bf16x8 afrag =
          *(const bf16x8*)&g[arow * DIM + (k0 ^ ((arow & 7) << 3))];
      acc[rt][0] = __builtin_amdgcn_mfma_f32_16x16x32_bf16(afrag, bfrag[0], acc[rt][0], 0, 0, 0);
      acc[rt][1] = __builtin_amdgcn_mfma_f32_16x16x32_bf16(afrag, bfrag[1], acc[rt][1], 0, 0, 0);
    }
  }

  // epilogue: C/D layout col=lane&15, row=(lane>>4)*4+reg
  float* ob = out + (size_t)b * NAGENT * DIM;
#pragma unroll
  for (int ct = 0; ct < 2; ++ct) {
    const int col = w * 32 + ct * 16 + lrow;
    const float bcv = bcw[col];
#pragma unroll
    for (int rt = 0; rt < 4; ++rt) {
#pragma unroll
      for (int r = 0; r < 4; ++r) {
        const int row = rt * 16 + lgrp * 4 + r;
        const float val = acc[rt][ct][r] + bcv;
        ob[row * DIM + col] = val > 0.f ? val : 0.f;
      }
    }
  }
}

extern "C" void kernel_launch(void* const* d_in, const int* in_sizes, int n_in,
                              void* d_out, int out_size, void* d_ws, size_t ws_size,
                              hipStream_t stream) {
  const float* h  = (const float*)d_in[0];  // hidden_state (16384,256)
  const float* Wa = (const float*)d_in[1];  // W_act (256,256)
  const float* ba = (const float*)d_in[2];  // b_act (256,)
  const float* Ws = (const float*)d_in[3];  // W_sum (256,256)
  const float* bs = (const float*)d_in[4];  // b_sum (256,)
  const float* Wh = (const float*)d_in[5];  // W_head (256,256)
  const float* bh = (const float*)d_in[6];  // b_head (256,)
  float* out = (float*)d_out;

  char* ws = (char*)d_ws;
  bf16_t* Wc  = (bf16_t*)ws;                 // 128 KB
  float*  bcw = (float*)(ws + 128 * 1024);   // 1 KB

  prep_kernel<<<NBATCH, 1024, 0, stream>>>(Wh, Ws, Wa, ba, bs, bh, Wc, bcw);
  fused_kernel<<<NBATCH, 512, 0, stream>>>(h, Wc, bcw, out);
}